// Round 2
// baseline (66786.676 us; speedup 1.0000x reference)
//
#include <hip/hip_runtime.h>
#include <math.h>

// Problem constants
#define B_ 32
#define T_ 512
#define N_ 512
#define D_ 4
#define H_ 2048
#define C_ 128

// ---------------- helpers ----------------
__device__ __forceinline__ float bflo(unsigned p) { return __uint_as_float(p << 16); }
__device__ __forceinline__ float bfhi(unsigned p) { return __uint_as_float(p & 0xffff0000u); }
__device__ __forceinline__ unsigned f2bf(float x) {
    unsigned u = __float_as_uint(x);
    return (u + 0x7fffu + ((u >> 16) & 1u)) >> 16;
}

// ---------------- generic f32 GEMM: C[M,N] = A[M,K] @ B[K,N] + bias[N] ----------------
// 128x128 tile, BK=16, 256 threads, 8x8 microtile. Requires M%128==0, N%128==0, K%16==0.
__global__ __launch_bounds__(256) void gemm_f32(
    const float* __restrict__ A, const float* __restrict__ Bm,
    const float* __restrict__ bias, float* __restrict__ C,
    int M, int N, int K) {
    __shared__ float As[16][132];
    __shared__ float Bs[16][132];
    const int tid = threadIdx.x;
    const int tx = tid & 15, ty = tid >> 4;
    const int bx = blockIdx.x, by = blockIdx.y;
    float acc[8][8];
#pragma unroll
    for (int i = 0; i < 8; ++i)
#pragma unroll
        for (int j = 0; j < 8; ++j) acc[i][j] = 0.f;
    const size_t Abase = (size_t)(by * 128) * K;
    for (int k0 = 0; k0 < K; k0 += 16) {
#pragma unroll
        for (int it = 0; it < 8; ++it) {
            int flat = it * 256 + tid;
            int r = flat >> 4, c = flat & 15;
            As[c][r] = A[Abase + (size_t)r * K + (k0 + c)];
        }
#pragma unroll
        for (int it = 0; it < 8; ++it) {
            int flat = it * 256 + tid;
            int r = flat >> 7, c = flat & 127;
            Bs[r][c] = Bm[(size_t)(k0 + r) * N + bx * 128 + c];
        }
        __syncthreads();
#pragma unroll
        for (int kk = 0; kk < 16; ++kk) {
            float a[8], bv[8];
            *(float4*)&a[0] = *(const float4*)&As[kk][ty * 8];
            *(float4*)&a[4] = *(const float4*)&As[kk][ty * 8 + 4];
            *(float4*)&bv[0] = *(const float4*)&Bs[kk][tx * 8];
            *(float4*)&bv[4] = *(const float4*)&Bs[kk][tx * 8 + 4];
#pragma unroll
            for (int i = 0; i < 8; ++i)
#pragma unroll
                for (int j = 0; j < 8; ++j)
                    acc[i][j] = fmaf(a[i], bv[j], acc[i][j]);
        }
        __syncthreads();
    }
#pragma unroll
    for (int i = 0; i < 8; ++i) {
        size_t row = (size_t)(by * 128 + ty * 8 + i);
#pragma unroll
        for (int j = 0; j < 8; ++j) {
            int col = bx * 128 + tx * 8 + j;
            C[row * (size_t)N + col] = acc[i][j] + bias[col];
        }
    }
}

// ---------------- LayerNorm + LeakyReLU over rows of H=2048, in place ----------------
__device__ __forceinline__ float block_sum256(float v, float* red) {
#pragma unroll
    for (int o = 32; o > 0; o >>= 1) v += __shfl_down(v, o, 64);
    int w = threadIdx.x >> 6;
    if ((threadIdx.x & 63) == 0) red[w] = v;
    __syncthreads();
    float r = red[0] + red[1] + red[2] + red[3];
    __syncthreads();
    return r;
}

__global__ __launch_bounds__(256) void ln_leaky_kernel(
    float* __restrict__ Z, const float* __restrict__ gam, const float* __restrict__ bet) {
    __shared__ float red[4];
    const size_t row = blockIdx.x;
    float* zr = Z + row * H_;
    const int tid = threadIdx.x;
    float v[8];
    float s = 0.f;
#pragma unroll
    for (int i = 0; i < 8; ++i) { v[i] = zr[tid + i * 256]; s += v[i]; }
    s = block_sum256(s, red);
    float mu = s * (1.f / H_);
    float q = 0.f;
#pragma unroll
    for (int i = 0; i < 8; ++i) { float d = v[i] - mu; q += d * d; }
    q = block_sum256(q, red);
    float rs = rsqrtf(q * (1.f / H_) + 1e-5f);
#pragma unroll
    for (int i = 0; i < 8; ++i) {
        int c = tid + i * 256;
        float y = (v[i] - mu) * rs * gam[c] + bet[c];
        zr[c] = y > 0.f ? y : 0.1f * y;
    }
}

// ---------------- persistent theta-scan kernel ----------------
// 256 blocks x 256 threads, 1 block/CU (LDS 115840B).
// Contention-free monotone-flag grid barrier: each block release-stores its own
// step counter to flags[blockIdx.x]; one wave per block polls all 256 flags
// (4/lane, device-scope acquire) until min(flags) >= target. No RMW atomics on
// a shared line -> no serialization across XCDs. Flags memset to 0 per launch.
__device__ __forceinline__ void grid_barrier(unsigned* flags, unsigned target) {
    __syncthreads();
    if (threadIdx.x == 0) {
        __hip_atomic_store(&flags[blockIdx.x], target, __ATOMIC_RELEASE,
                           __HIP_MEMORY_SCOPE_AGENT);
    }
    if (threadIdx.x < 64) {
        const unsigned* f = flags + threadIdx.x * 4;
        unsigned spins = 0;
        for (;;) {
            unsigned m0 = __hip_atomic_load(f + 0, __ATOMIC_ACQUIRE, __HIP_MEMORY_SCOPE_AGENT);
            unsigned m1 = __hip_atomic_load(f + 1, __ATOMIC_ACQUIRE, __HIP_MEMORY_SCOPE_AGENT);
            unsigned m2 = __hip_atomic_load(f + 2, __ATOMIC_ACQUIRE, __HIP_MEMORY_SCOPE_AGENT);
            unsigned m3 = __hip_atomic_load(f + 3, __ATOMIC_ACQUIRE, __HIP_MEMORY_SCOPE_AGENT);
            unsigned mn = min(min(m0, m1), min(m2, m3));
            if (__all(mn >= target)) break;
            __builtin_amdgcn_s_sleep(1);
            if (++spins > (1u << 22)) break;  // deadlock -> wrong answer, not hang
        }
    }
    __syncthreads();
}

#define SCAN_LDS_BYTES 115840

__global__ __launch_bounds__(256, 1) void scan_kernel(
    const float* __restrict__ sc, const float* __restrict__ gamma,
    const float* __restrict__ omega, const float* __restrict__ Wm,
    const float* __restrict__ bm, float* __restrict__ feat,
    unsigned* __restrict__ stct,   // [2][512*128] packed bf16 (hi=cos, lo=sin), [j][bd]
    float* __restrict__ g_ring,    // [4][B_*N_]
    float* __restrict__ mh_ring,   // [4][B_*N_]
    unsigned* __restrict__ flags) {
    extern __shared__ char smem[];
    float* sc_lds = (float*)smem;                              // [32][516] f32
    unsigned* stct_lds = (unsigned*)(smem + 66048);            // [8][516]  u32
    unsigned short* g_lds = (unsigned short*)(smem + 82560);   // [32][520] bf16
    const int tid = threadIdx.x;
    const int ig = blockIdx.x >> 4, bg = blockIdx.x & 15;
    const int i_loc = tid >> 3, bd_loc = tid & 7;
    const int i = ig * 32 + i_loc;
    const int bd = (bg << 3) + bd_loc;
    const int b = bd >> 2, d = bd & 3;
    const bool isB = blockIdx.x < 64;            // blocks doing the mask GEMM
    const int Bb = tid >> 3;                     // 0..31
    const int Bn = (blockIdx.x << 3) + (tid & 7);
    unsigned bar_no = 0;

    // persistent sc tile: rows [ig*32, ig*32+32)
    for (int it = 0; it < 64; ++it) {
        int flat = it * 256 + tid;
        int r = flat >> 9, c = flat & 511;
        sc_lds[r * 516 + c] = sc[(size_t)(ig * 32 + r) * 512 + c];
    }
    const float omega_v = omega[i * 4 + d];
    const float bmask_v = isB ? bm[Bn] : 0.f;
    const float KdN = 1.0f / 512.0f;
    float theta = 0.f;
    float s_prev = 0.f, c_prev = 1.f;  // sin/cos of carried theta

    for (int t = 0; t < T_; ++t) {
        // -------- staging (reads synced at end of previous step) --------
        if (t > 0) {
            const unsigned* src = stct + (size_t)(t & 1) * 65536;
#pragma unroll
            for (int it = 0; it < 16; ++it) {
                int flat = it * 256 + tid;
                stct_lds[(flat & 7) * 516 + (flat >> 3)] =
                    src[(size_t)(flat >> 3) * 128 + (bg << 3) + (flat & 7)];
            }
            if (isB) {
                const float* gs = g_ring + (size_t)((t - 1) & 3) * (B_ * N_);
#pragma unroll
                for (int it = 0; it < 64; ++it) {
                    int flat = it * 256 + tid;
                    g_lds[(flat >> 9) * 520 + (flat & 511)] = (unsigned short)f2bf(gs[flat]);
                }
            }
        }
        __syncthreads();

        // -------- B work: mask_h for step t+1 (g from meanTheta_{t-1}) --------
        if (isB && t > 0) {
            float acc = 0.f;
            const unsigned short* gr = g_lds + Bb * 520;
#pragma unroll 4
            for (int m = 0; m < 512; ++m)
                acc = fmaf(__uint_as_float((unsigned)gr[m] << 16), Wm[(size_t)m * 512 + Bn], acc);
            float mh = 1.f / (1.f + expf(-(acc + bmask_v)));
            mh_ring[(size_t)((t + 1) & 3) * (B_ * N_) + Bb * 512 + Bn] = mh;
        }

        // -------- A work: coupling dot + theta update --------
        float Sst = 0.f, Sct = 0.f;
        if (t > 0) {
            const float* scrow = sc_lds + i_loc * 516;
            const unsigned* prow = stct_lds + bd_loc * 516;
#pragma unroll 2
            for (int j = 0; j < 512; j += 4) {
                float4 s4 = *(const float4*)(scrow + j);
                uint4 p4 = *(const uint4*)(prow + j);
                Sst = fmaf(s4.x, bflo(p4.x), Sst); Sct = fmaf(s4.x, bfhi(p4.x), Sct);
                Sst = fmaf(s4.y, bflo(p4.y), Sst); Sct = fmaf(s4.y, bfhi(p4.y), Sct);
                Sst = fmaf(s4.z, bflo(p4.z), Sst); Sct = fmaf(s4.z, bfhi(p4.z), Sct);
                Sst = fmaf(s4.w, bflo(p4.w), Sst); Sct = fmaf(s4.w, bfhi(p4.w), Sct);
            }
        }
        float coup = c_prev * Sst - s_prev * Sct;
        float gamma_v = gamma[(size_t)(b * T_ + t) * 512 + i];
        theta += 0.1f * (omega_v + gamma_v + KdN * coup);
        sincosf(theta, &s_prev, &c_prev);  // now sin/cos of theta_new
        stct[(size_t)((t + 1) & 1) * 65536 + i * 128 + bd] = (f2bf(c_prev) << 16) | f2bf(s_prev);
        float msum = theta;
        msum += __shfl_xor(msum, 1, 64);
        msum += __shfl_xor(msum, 2, 64);
        if (d == 0)
            g_ring[(size_t)(t & 3) * (B_ * N_) + b * 512 + i] = 0.5f + 0.5f * sinf(msum * 0.25f);

        // -------- bootstrap at t==0: compute mask_h for steps 0,1,2 --------
        if (t == 0) {
            grid_barrier(flags, ++bar_no);
            if (isB) {
                float acc = 0.f;
                for (int m = 0; m < 512; ++m)
                    acc = fmaf(g_ring[Bb * 512 + m], Wm[(size_t)m * 512 + Bn], acc);
                float mh = 1.f / (1.f + expf(-(acc + bmask_v)));
                mh_ring[Bb * 512 + Bn] = mh;
                mh_ring[(B_ * N_) + Bb * 512 + Bn] = mh;
                mh_ring[2 * (B_ * N_) + Bb * 512 + Bn] = mh;
            }
            grid_barrier(flags, ++bar_no);
        }

        // -------- feat_t = sin(theta_new) * g_t * mask_h_t --------
        int dslot = (t >= 2) ? ((t - 2) & 3) : 0;
        float gv = g_ring[(size_t)dslot * (B_ * N_) + b * 512 + i];
        float mhv = mh_ring[(size_t)(t & 3) * (B_ * N_) + b * 512 + i];
        feat[(size_t)(b * T_ + t) * 2048 + i * 4 + d] = s_prev * gv * mhv;

        grid_barrier(flags, ++bar_no);
    }
}

// ---------------- LIF membrane scan: cur -> spike, in place on [B,T,H] ----------------
__global__ __launch_bounds__(256) void mem_scan_kernel(float* __restrict__ io) {
    int tid = blockIdx.x * 256 + threadIdx.x;  // 65536 = B*H
    int h = tid & (H_ - 1), b = tid >> 11;
    float mem = 0.f;
    float* base = io + (size_t)b * T_ * H_ + h;
    for (int t = 0; t < T_; ++t) {
        float cur = base[(size_t)t * H_];
        mem = 0.5f * mem + cur;
        float sp = 1.f / (1.f + expf(-4.f * (mem - 1.f)));
        mem -= sp;
        base[(size_t)t * H_] = sp;
    }
}

// ---------------- conv1d(k=5,pad=2) over T + log_softmax over C ----------------
// snn: [B*T, 128] rows (b*T+t). out0: [B,128,512].
__global__ __launch_bounds__(128) void conv_lsm_kernel(
    const float* __restrict__ snn, const float* __restrict__ Wc,
    const float* __restrict__ bc, float* __restrict__ out0) {
    __shared__ float sl[36 * 128];  // staged input rows tt0-2 .. tt0+33 ; reused for cl[32][129]
    const int b = blockIdx.x >> 4;
    const int tt0 = (blockIdx.x & 15) * 32;
    const int co = threadIdx.x;
    for (int r = 0; r < 36; ++r) {
        int t = tt0 + r - 2;
        sl[r * 128 + co] = (t >= 0 && t < T_) ? snn[(size_t)(b * T_ + t) * 128 + co] : 0.f;
    }
    __syncthreads();
    float acc[32];
#pragma unroll
    for (int i = 0; i < 32; ++i) acc[i] = 0.f;
    for (int ci = 0; ci < 128; ++ci) {
        const float* wp = &Wc[(size_t)(co * 128 + ci) * 5];
        float w0 = wp[0], w1 = wp[1], w2 = wp[2], w3 = wp[3], w4 = wp[4];
        const float* col = &sl[ci];
        float r0 = col[0 * 128], r1 = col[1 * 128], r2 = col[2 * 128], r3 = col[3 * 128];
#pragma unroll
        for (int i = 0; i < 32; ++i) {
            float r4 = col[(i + 4) * 128];
            acc[i] += w0 * r0 + w1 * r1 + w2 * r2 + w3 * r3 + w4 * r4;
            r0 = r1; r1 = r2; r2 = r3; r3 = r4;
        }
    }
    float bco = bc[co];
    __syncthreads();  // everyone done reading sl
    float* cl = sl;   // [32][129]
#pragma unroll
    for (int i = 0; i < 32; ++i) cl[i * 129 + co] = acc[i] + bco;
    __syncthreads();
    if (co < 32) {
        int t = tt0 + co;
        float mx = -3.4e38f;
        for (int c = 0; c < 128; ++c) mx = fmaxf(mx, cl[co * 129 + c]);
        float se = 0.f;
        for (int c = 0; c < 128; ++c) se += expf(cl[co * 129 + c] - mx);
        float lse = mx + logf(se);
        for (int c = 0; c < 128; ++c)
            out0[((size_t)(b * 128 + c)) * T_ + t] = cl[co * 129 + c] - lse;
    }
}

// ---------------- launch ----------------
extern "C" void kernel_launch(void* const* d_in, const int* in_sizes, int n_in,
                              void* d_out, int out_size, void* d_ws, size_t ws_size,
                              hipStream_t stream) {
    (void)in_sizes; (void)n_in; (void)out_size; (void)ws_size;
    const float* x      = (const float*)d_in[0];   // [B,T,N]
    const float* sc     = (const float*)d_in[1];   // [N,N]
    const float* W_proj = (const float*)d_in[2];   // [N,H]
    const float* b_proj = (const float*)d_in[3];
    const float* ln_g   = (const float*)d_in[4];
    const float* ln_b   = (const float*)d_in[5];
    const float* W_enc  = (const float*)d_in[6];   // [H,N]
    const float* b_enc  = (const float*)d_in[7];
    const float* omega  = (const float*)d_in[8];   // [N,D]
    const float* W_mask = (const float*)d_in[9];   // [N,N]
    const float* b_mask = (const float*)d_in[10];
    const float* W_in   = (const float*)d_in[11];  // [N*D,H]
    const float* b_in   = (const float*)d_in[12];
    const float* W_out  = (const float*)d_in[13];  // [H,C]
    const float* b_out  = (const float*)d_in[14];
    const float* W_conv = (const float*)d_in[15];  // [C,C,5]
    const float* b_conv = (const float*)d_in[16];

    float* out0 = (float*)d_out;                   // [B,C,T] = 2,097,152 floats
    float* out1 = out0 + (size_t)B_ * C_ * T_;     // [B,T,H] = 33,554,432 floats (also Z / cur scratch)

    const int M = B_ * T_;  // 16384
    char* w = (char*)d_ws;
    unsigned* flags = (unsigned*)w;                               // 256 u32 (4KB reserved)
    float* gamma    = (float*)(w + 4096);                         // [M, N] 33.5 MB
    float* feat     = gamma + (size_t)M * N_;                     // [M, N*D] 134.2 MB
    unsigned* stct  = (unsigned*)(feat + (size_t)M * N_ * D_);    // [2][65536] 0.5 MB
    float* g_ring   = (float*)(stct + 2 * 65536);                 // [4][16384]
    float* mh_ring  = g_ring + 4 * (B_ * N_);                     // [4][16384]
    float* snn_pre  = gamma;                                      // reuse (gamma dead after scan)

    hipMemsetAsync(flags, 0, 4096, stream);

    // G1: Z = x @ W_proj + b_proj   -> out1 (as Z scratch)
    gemm_f32<<<dim3(H_ / 128, M / 128), 256, 0, stream>>>(x, W_proj, b_proj, out1, M, H_, N_);
    // LN + LeakyReLU in place
    ln_leaky_kernel<<<M, 256, 0, stream>>>(out1, ln_g, ln_b);
    // G2: gamma = Z @ W_enc + b_enc
    gemm_f32<<<dim3(N_ / 128, M / 128), 256, 0, stream>>>(out1, W_enc, b_enc, gamma, M, N_, H_);
    // persistent theta scan -> feat
    scan_kernel<<<256, 256, SCAN_LDS_BYTES, stream>>>(sc, gamma, omega, W_mask, b_mask,
                                                      feat, stct, g_ring, mh_ring, flags);
    // G3: cur = feat @ W_in + b_in  -> out1 (overwrites Z)
    gemm_f32<<<dim3(H_ / 128, M / 128), 256, 0, stream>>>(feat, W_in, b_in, out1, M, H_, N_ * D_);
    // LIF membrane scan: cur -> spikes in place (final output 1)
    mem_scan_kernel<<<256, 256, 0, stream>>>(out1);
    // G4: snn_pre = spikes @ W_out + b_out
    gemm_f32<<<dim3(C_ / 128, M / 128), 256, 0, stream>>>(out1, W_out, b_out, snn_pre, M, C_, H_);
    // conv1d + log_softmax -> out0
    conv_lsm_kernel<<<dim3(B_ * 16), 128, 0, stream>>>(snn_pre, W_conv, b_conv, out0);
}

// Round 3
// 8851.562 us; speedup vs baseline: 7.5452x; 7.5452x over previous
//
#include <hip/hip_runtime.h>
#include <math.h>

// Problem constants
#define B_ 32
#define T_ 512
#define N_ 512
#define D_ 4
#define H_ 2048
#define C_ 128

typedef __attribute__((ext_vector_type(8))) short short8_t;
typedef __attribute__((ext_vector_type(4))) float float4_t;

// ---------------- helpers ----------------
__device__ __forceinline__ float bflo(unsigned p) { return __uint_as_float(p << 16); }
__device__ __forceinline__ float bfhi(unsigned p) { return __uint_as_float(p & 0xffff0000u); }
__device__ __forceinline__ unsigned f2bf(float x) {
    unsigned u = __float_as_uint(x);
    return (u + 0x7fffu + ((u >> 16) & 1u)) >> 16;
}
__device__ __forceinline__ float sigm(float x) { return 1.f / (1.f + expf(-x)); }

// ---------------- generic f32 GEMM: C[M,N] = A[M,K] @ B[K,N] + bias[N] ----------------
__global__ __launch_bounds__(256) void gemm_f32(
    const float* __restrict__ A, const float* __restrict__ Bm,
    const float* __restrict__ bias, float* __restrict__ C,
    int M, int N, int K) {
    __shared__ float As[16][132];
    __shared__ float Bs[16][132];
    const int tid = threadIdx.x;
    const int tx = tid & 15, ty = tid >> 4;
    const int bx = blockIdx.x, by = blockIdx.y;
    float acc[8][8];
#pragma unroll
    for (int i = 0; i < 8; ++i)
#pragma unroll
        for (int j = 0; j < 8; ++j) acc[i][j] = 0.f;
    const size_t Abase = (size_t)(by * 128) * K;
    for (int k0 = 0; k0 < K; k0 += 16) {
#pragma unroll
        for (int it = 0; it < 8; ++it) {
            int flat = it * 256 + tid;
            int r = flat >> 4, c = flat & 15;
            As[c][r] = A[Abase + (size_t)r * K + (k0 + c)];
        }
#pragma unroll
        for (int it = 0; it < 8; ++it) {
            int flat = it * 256 + tid;
            int r = flat >> 7, c = flat & 127;
            Bs[r][c] = Bm[(size_t)(k0 + r) * N + bx * 128 + c];
        }
        __syncthreads();
#pragma unroll
        for (int kk = 0; kk < 16; ++kk) {
            float a[8], bv[8];
            *(float4*)&a[0] = *(const float4*)&As[kk][ty * 8];
            *(float4*)&a[4] = *(const float4*)&As[kk][ty * 8 + 4];
            *(float4*)&bv[0] = *(const float4*)&Bs[kk][tx * 8];
            *(float4*)&bv[4] = *(const float4*)&Bs[kk][tx * 8 + 4];
#pragma unroll
            for (int i = 0; i < 8; ++i)
#pragma unroll
                for (int j = 0; j < 8; ++j)
                    acc[i][j] = fmaf(a[i], bv[j], acc[i][j]);
        }
        __syncthreads();
    }
#pragma unroll
    for (int i = 0; i < 8; ++i) {
        size_t row = (size_t)(by * 128 + ty * 8 + i);
#pragma unroll
        for (int j = 0; j < 8; ++j) {
            int col = bx * 128 + tx * 8 + j;
            C[row * (size_t)N + col] = acc[i][j] + bias[col];
        }
    }
}

// ---------------- LayerNorm + LeakyReLU over rows of H=2048, in place ----------------
__device__ __forceinline__ float block_sum256(float v, float* red) {
#pragma unroll
    for (int o = 32; o > 0; o >>= 1) v += __shfl_down(v, o, 64);
    int w = threadIdx.x >> 6;
    if ((threadIdx.x & 63) == 0) red[w] = v;
    __syncthreads();
    float r = red[0] + red[1] + red[2] + red[3];
    __syncthreads();
    return r;
}

__global__ __launch_bounds__(256) void ln_leaky_kernel(
    float* __restrict__ Z, const float* __restrict__ gam, const float* __restrict__ bet) {
    __shared__ float red[4];
    const size_t row = blockIdx.x;
    float* zr = Z + row * H_;
    const int tid = threadIdx.x;
    float v[8];
    float s = 0.f;
#pragma unroll
    for (int i = 0; i < 8; ++i) { v[i] = zr[tid + i * 256]; s += v[i]; }
    s = block_sum256(s, red);
    float mu = s * (1.f / H_);
    float q = 0.f;
#pragma unroll
    for (int i = 0; i < 8; ++i) { float d = v[i] - mu; q += d * d; }
    q = block_sum256(q, red);
    float rs = rsqrtf(q * (1.f / H_) + 1e-5f);
#pragma unroll
    for (int i = 0; i < 8; ++i) {
        int c = tid + i * 256;
        float y = (v[i] - mu) * rs * gam[c] + bet[c];
        zr[c] = y > 0.f ? y : 0.1f * y;
    }
}

// ---------------- persistent theta-scan: 128 blocks x 512 threads ----------------
// block: ig = blockIdx>>4 (i-rows [ig*64,+64)), bg = blockIdx&15 (bd slice [bg*8,+8)
//        = batches {2bg, 2bg+1} x d 0..3).
// Group(bg) = 8 blocks {bg + 16*ig}: only these share the per-step st/ct exchange.
// Per-step sync = 8-block flag barrier (one 128B line per group).
// sc row-slice (bf16) and W_mask^T col-slice (bf16) are LDS-resident.
// Coupling via mfma_f32_16x16x32_bf16: A = sc slice, B = [st(8) | ct(8)] cols.

#define SCAN_LDS_BYTES 154368
// LDS offsets (bytes)
#define OFF_SC   0        // [64][520] u16
#define OFF_WMT  66560    // [64][520] u16
#define OFF_XT   133120   // [16][520] u16
#define OFF_GST  149760   // [2][512] f32
#define OFF_MH   153856   // [2][64]  f32

__device__ __forceinline__ void group_post_wait(unsigned* flags, int bg, int ig,
                                                unsigned target, unsigned& dead) {
    const int tid = threadIdx.x;
    if (tid == 0) {
        __threadfence();
        __hip_atomic_store(&flags[bg * 32 + ig], target, __ATOMIC_RELEASE,
                           __HIP_MEMORY_SCOPE_AGENT);
    }
    if (tid < 64 && !dead) {
        unsigned spins = 0;
        for (;;) {
            unsigned v = (tid < 8)
                ? __hip_atomic_load(&flags[bg * 32 + tid], __ATOMIC_ACQUIRE,
                                    __HIP_MEMORY_SCOPE_AGENT)
                : target;
            if (__all(v >= target)) break;
            __builtin_amdgcn_s_sleep(1);
            if (++spins > (1u << 16)) { dead = 1; break; }  // no-hang escape
        }
    }
    __syncthreads();
}

__global__ __launch_bounds__(512, 1) void scan_kernel(
    const float* __restrict__ sc, const float* __restrict__ gamma,
    const float* __restrict__ omega, const float* __restrict__ Wm,
    const float* __restrict__ bm, float* __restrict__ feat,
    unsigned* __restrict__ stct_glob,  // [2][16][8][512] u32 (lo=sin bf16, hi=cos bf16)
    float* __restrict__ g_glob,        // [4][16][2][512] f32
    unsigned* __restrict__ flags) {
    extern __shared__ char smem[];
    unsigned short* sc_lds = (unsigned short*)(smem + OFF_SC);
    unsigned short* WmT    = (unsigned short*)(smem + OFF_WMT);
    unsigned short* XT     = (unsigned short*)(smem + OFF_XT);
    float* g_stage         = (float*)(smem + OFF_GST);
    float* mh_lds          = (float*)(smem + OFF_MH);

    const int tid = threadIdx.x;
    const int bg = blockIdx.x & 15;
    const int ig = blockIdx.x >> 4;
    const int wv = tid >> 6;
    const int l = tid & 63;

    // ---- one-time LDS loads: sc slice + Wm^T slice, f32 -> bf16 ----
    for (int it = 0; it < 32; ++it) {
        int flat = it * 512 + tid;
        int r = flat >> 8, c2 = (flat & 255) * 2;
        float v0 = sc[(size_t)(ig * 64 + r) * 512 + c2];
        float v1 = sc[(size_t)(ig * 64 + r) * 512 + c2 + 1];
        ((unsigned*)sc_lds)[r * 260 + (c2 >> 1)] = f2bf(v0) | (f2bf(v1) << 16);
    }
    for (int it = 0; it < 32; ++it) {
        int flat = it * 512 + tid;
        int nl = flat & 63, m2 = (flat >> 6) * 2;
        float v0 = Wm[(size_t)m2 * 512 + ig * 64 + nl];
        float v1 = Wm[(size_t)(m2 + 1) * 512 + ig * 64 + nl];
        ((unsigned*)WmT)[nl * 260 + (m2 >> 1)] = f2bf(v0) | (f2bf(v1) << 16);
    }

    // ---- per-lane constants ----
    // coupling lanes (wv<4): MFMA C layout: row=(l>>4)*4+r, col=l&15
    const int n = l & 15;
    const int bdl = l & 7;
    const int b_loc = bdl >> 2, d = bdl & 3;
    const int iC = wv * 16 + (l >> 4) * 4;     // + r  (local row for theta ownership)
    const int bglob = 2 * bg + b_loc;
    float om[4];
    if (wv < 4) {
#pragma unroll
        for (int r = 0; r < 4; ++r)
            om[r] = omega[(size_t)(ig * 64 + iC + r) * 4 + d];
    }
    // mask lanes (wv>=4)
    const int sid = tid & 255;
    const int w4 = sid >> 6, ml = sid & 63;
    const int n_loc = (w4 & 1) * 32 + (ml & 31);
    const int mbl = w4 >> 1;
    const int mhalf = (ml >> 5) * 256;
    const float bmv = (wv >= 4) ? bm[ig * 64 + n_loc] : 0.f;

    float th[4] = {0.f, 0.f, 0.f, 0.f};
    float sn[4] = {0.f, 0.f, 0.f, 0.f};
    float cs[4] = {1.f, 1.f, 1.f, 1.f};
    unsigned bar = 0, dead = 0;

#define MASK_BODY() do {                                                          \
    float acc_ = 0.f;                                                             \
    const unsigned* wrow = (const unsigned*)WmT + n_loc * 260 + (mhalf >> 1);     \
    const float* grow = g_stage + mbl * 512 + mhalf;                              \
    _Pragma("unroll 4")                                                           \
    for (int itm = 0; itm < 32; ++itm) {                                          \
        uint4 w4v = *(const uint4*)(wrow + itm * 4);                              \
        float4 ga = *(const float4*)(grow + itm * 8);                             \
        float4 gb = *(const float4*)(grow + itm * 8 + 4);                         \
        acc_ = fmaf(bflo(w4v.x), ga.x, acc_); acc_ = fmaf(bfhi(w4v.x), ga.y, acc_);\
        acc_ = fmaf(bflo(w4v.y), ga.z, acc_); acc_ = fmaf(bfhi(w4v.y), ga.w, acc_);\
        acc_ = fmaf(bflo(w4v.z), gb.x, acc_); acc_ = fmaf(bfhi(w4v.z), gb.y, acc_);\
        acc_ = fmaf(bflo(w4v.w), gb.z, acc_); acc_ = fmaf(bfhi(w4v.w), gb.w, acc_);\
    }                                                                             \
    acc_ += __shfl_xor(acc_, 32, 64);                                             \
    if (ml < 32) mh_lds[mbl * 64 + n_loc] = sigm(acc_ + bmv);                     \
} while (0)

    for (int t = 0; t < T_; ++t) {
        float gmv[4];
        // ---- staging phase ----
        if (wv >= 4) {
            if (t >= 1) {
                const unsigned* src = stct_glob + (size_t)(((t - 1) & 1) * 16 + bg) * 8 * 512;
#pragma unroll
                for (int q = 0; q < 2; ++q) {
                    int item = q * 256 + sid;
                    int bdl2 = item >> 6, j0 = (item & 63) * 8;
                    const unsigned* p = src + bdl2 * 512 + j0;
                    uint4 u0 = *(const uint4*)p;
                    uint4 u1 = *(const uint4*)(p + 4);
                    uint4 sv, cv;
                    sv.x = (u0.x & 0xffffu) | (u0.y << 16);
                    sv.y = (u0.z & 0xffffu) | (u0.w << 16);
                    sv.z = (u1.x & 0xffffu) | (u1.y << 16);
                    sv.w = (u1.z & 0xffffu) | (u1.w << 16);
                    cv.x = (u0.x >> 16) | (u0.y & 0xffff0000u);
                    cv.y = (u0.z >> 16) | (u0.w & 0xffff0000u);
                    cv.z = (u1.x >> 16) | (u1.y & 0xffff0000u);
                    cv.w = (u1.z >> 16) | (u1.w & 0xffff0000u);
                    *(uint4*)((unsigned*)XT + bdl2 * 260 + (j0 >> 1)) = sv;
                    *(uint4*)((unsigned*)XT + (bdl2 + 8) * 260 + (j0 >> 1)) = cv;
                }
            }
            if (t >= 3) {
                const float* gsrc = g_glob + (size_t)(((t - 2) & 3) * 16 + bg) * 2 * 512;
                *(float4*)&g_stage[sid * 4] = *(const float4*)&gsrc[sid * 4];
            }
        } else {
#pragma unroll
            for (int r = 0; r < 4; ++r)
                gmv[r] = gamma[(size_t)(bglob * 512 + t) * 512 + (ig * 64 + iC + r)];
        }
        __syncthreads();  // sync1

        // ---- compute phase ----
        if (wv < 4) {
            float4_t acc = {0.f, 0.f, 0.f, 0.f};
            if (t >= 1) {
                const unsigned short* arow = sc_lds + (wv * 16 + (l & 15)) * 520;
                const unsigned short* brow = XT + (l & 15) * 520;
                const int koff = (l >> 4) * 8;
#pragma unroll
                for (int k0 = 0; k0 < 16; ++k0) {
                    short8_t av = *(const short8_t*)(arow + k0 * 32 + koff);
                    short8_t bv = *(const short8_t*)(brow + k0 * 32 + koff);
                    acc = __builtin_amdgcn_mfma_f32_16x16x32_bf16(av, bv, acc, 0, 0, 0);
                }
            }
#pragma unroll
            for (int r = 0; r < 4; ++r) {
                float other = __shfl_xor(acc[r], 8, 64);
                float Sst = (n < 8) ? acc[r] : other;
                float Sct = (n < 8) ? other : acc[r];
                float coup = cs[r] * Sst - sn[r] * Sct;
                th[r] += 0.1f * (om[r] + gmv[r] + (1.f / 512.f) * coup);
                sincosf(th[r], &sn[r], &cs[r]);
            }
            if (n < 8) {
                unsigned* dst = stct_glob + (size_t)((t & 1) * 16 + bg) * 8 * 512 +
                                bdl * 512 + (ig * 64 + iC);
#pragma unroll
                for (int r = 0; r < 4; ++r)
                    dst[r] = f2bf(sn[r]) | (f2bf(cs[r]) << 16);
            }
            // g = 0.5*(1+sin(mean_d theta_new))
            float gnew[4];
#pragma unroll
            for (int r = 0; r < 4; ++r) {
                float m1 = th[r] + __shfl_xor(th[r], 1, 64);
                float m2 = m1 + __shfl_xor(m1, 2, 64);
                gnew[r] = 0.5f + 0.5f * sinf(m2 * 0.25f);
            }
            if (n < 8 && d == 0) {
                float* gd = g_glob + (size_t)((t & 3) * 16 + bg) * 2 * 512 +
                            b_loc * 512 + (ig * 64 + iC);
#pragma unroll
                for (int r = 0; r < 4; ++r) gd[r] = gnew[r];
            }
        } else {
            if (t >= 3) MASK_BODY();
        }

        // ---- t==0 bootstrap: publish g(0), group-sync, then mask from g(0) ----
        if (t == 0) {
            __syncthreads();
            group_post_wait(flags, bg, ig, ++bar, dead);
            if (wv >= 4) {
                const float* gsrc = g_glob + (size_t)(0 * 16 + bg) * 2 * 512;
                *(float4*)&g_stage[sid * 4] = *(const float4*)&gsrc[sid * 4];
            }
            __syncthreads();
            if (wv >= 4) MASK_BODY();
        }
        __syncthreads();  // sync2: mh_lds/g_stage ready, XT reads done

        // ---- feat = sin(theta_new) * g_{t-2} * mh_t ----
        if (wv < 4 && n < 8) {
#pragma unroll
            for (int r = 0; r < 4; ++r) {
                float gv = g_stage[b_loc * 512 + (ig * 64 + iC + r)];
                float mhv = mh_lds[b_loc * 64 + (iC + r)];
                feat[(size_t)(bglob * 512 + t) * 2048 + (ig * 64 + iC + r) * 4 + d] =
                    sn[r] * gv * mhv;
            }
        }
        // ---- end-of-step group barrier ----
        group_post_wait(flags, bg, ig, ++bar, dead);
    }
#undef MASK_BODY
}

// ---------------- LIF membrane scan: cur -> spike, in place on [B,T,H] ----------------
__global__ __launch_bounds__(256) void mem_scan_kernel(float* __restrict__ io) {
    int tid = blockIdx.x * 256 + threadIdx.x;  // 65536 = B*H
    int h = tid & (H_ - 1), b = tid >> 11;
    float mem = 0.f;
    float* base = io + (size_t)b * T_ * H_ + h;
    for (int t = 0; t < T_; ++t) {
        float cur = base[(size_t)t * H_];
        mem = 0.5f * mem + cur;
        float sp = 1.f / (1.f + expf(-4.f * (mem - 1.f)));
        mem -= sp;
        base[(size_t)t * H_] = sp;
    }
}

// ---------------- conv1d(k=5,pad=2) over T + log_softmax over C ----------------
__global__ __launch_bounds__(128) void conv_lsm_kernel(
    const float* __restrict__ snn, const float* __restrict__ Wc,
    const float* __restrict__ bc, float* __restrict__ out0) {
    __shared__ float sl[36 * 128];
    const int b = blockIdx.x >> 4;
    const int tt0 = (blockIdx.x & 15) * 32;
    const int co = threadIdx.x;
    for (int r = 0; r < 36; ++r) {
        int t = tt0 + r - 2;
        sl[r * 128 + co] = (t >= 0 && t < T_) ? snn[(size_t)(b * T_ + t) * 128 + co] : 0.f;
    }
    __syncthreads();
    float acc[32];
#pragma unroll
    for (int i = 0; i < 32; ++i) acc[i] = 0.f;
    for (int ci = 0; ci < 128; ++ci) {
        const float* wp = &Wc[(size_t)(co * 128 + ci) * 5];
        float w0 = wp[0], w1 = wp[1], w2 = wp[2], w3 = wp[3], w4 = wp[4];
        const float* col = &sl[ci];
        float r0 = col[0 * 128], r1 = col[1 * 128], r2 = col[2 * 128], r3 = col[3 * 128];
#pragma unroll
        for (int i = 0; i < 32; ++i) {
            float r4 = col[(i + 4) * 128];
            acc[i] += w0 * r0 + w1 * r1 + w2 * r2 + w3 * r3 + w4 * r4;
            r0 = r1; r1 = r2; r2 = r3; r3 = r4;
        }
    }
    float bco = bc[co];
    __syncthreads();
    float* cl = sl;
#pragma unroll
    for (int i = 0; i < 32; ++i) cl[i * 129 + co] = acc[i] + bco;
    __syncthreads();
    if (co < 32) {
        int t = tt0 + co;
        float mx = -3.4e38f;
        for (int c = 0; c < 128; ++c) mx = fmaxf(mx, cl[co * 129 + c]);
        float se = 0.f;
        for (int c = 0; c < 128; ++c) se += expf(cl[co * 129 + c] - mx);
        float lse = mx + logf(se);
        for (int c = 0; c < 128; ++c)
            out0[((size_t)(b * 128 + c)) * T_ + t] = cl[co * 129 + c] - lse;
    }
}

// ---------------- launch ----------------
extern "C" void kernel_launch(void* const* d_in, const int* in_sizes, int n_in,
                              void* d_out, int out_size, void* d_ws, size_t ws_size,
                              hipStream_t stream) {
    (void)in_sizes; (void)n_in; (void)out_size; (void)ws_size;
    const float* x      = (const float*)d_in[0];
    const float* sc     = (const float*)d_in[1];
    const float* W_proj = (const float*)d_in[2];
    const float* b_proj = (const float*)d_in[3];
    const float* ln_g   = (const float*)d_in[4];
    const float* ln_b   = (const float*)d_in[5];
    const float* W_enc  = (const float*)d_in[6];
    const float* b_enc  = (const float*)d_in[7];
    const float* omega  = (const float*)d_in[8];
    const float* W_mask = (const float*)d_in[9];
    const float* b_mask = (const float*)d_in[10];
    const float* W_in   = (const float*)d_in[11];
    const float* b_in   = (const float*)d_in[12];
    const float* W_out  = (const float*)d_in[13];
    const float* b_out  = (const float*)d_in[14];
    const float* W_conv = (const float*)d_in[15];
    const float* b_conv = (const float*)d_in[16];

    float* out0 = (float*)d_out;                   // [B,C,T]
    float* out1 = out0 + (size_t)B_ * C_ * T_;     // [B,T,H] spikes (also Z/cur scratch)

    const int M = B_ * T_;  // 16384
    char* w = (char*)d_ws;
    unsigned* flags = (unsigned*)w;                               // 16 groups x 128B
    float* gamma    = (float*)(w + 4096);                         // [M, N]
    float* feat     = gamma + (size_t)M * N_;                     // [M, N*D]
    unsigned* stct  = (unsigned*)(feat + (size_t)M * N_ * D_);    // [2][16][8][512]
    float* g_glob   = (float*)(stct + 2 * 16 * 8 * 512);          // [4][16][2][512]
    float* snn_pre  = gamma;                                      // reuse post-scan

    hipMemsetAsync(flags, 0, 4096, stream);

    gemm_f32<<<dim3(H_ / 128, M / 128), 256, 0, stream>>>(x, W_proj, b_proj, out1, M, H_, N_);
    ln_leaky_kernel<<<M, 256, 0, stream>>>(out1, ln_g, ln_b);
    gemm_f32<<<dim3(N_ / 128, M / 128), 256, 0, stream>>>(out1, W_enc, b_enc, gamma, M, N_, H_);
    scan_kernel<<<128, 512, SCAN_LDS_BYTES, stream>>>(sc, gamma, omega, W_mask, b_mask,
                                                      feat, stct, g_glob, flags);
    gemm_f32<<<dim3(H_ / 128, M / 128), 256, 0, stream>>>(feat, W_in, b_in, out1, M, H_, N_ * D_);
    mem_scan_kernel<<<256, 256, 0, stream>>>(out1);
    gemm_f32<<<dim3(C_ / 128, M / 128), 256, 0, stream>>>(out1, W_out, b_out, snn_pre, M, C_, H_);
    conv_lsm_kernel<<<dim3(B_ * 16), 128, 0, stream>>>(snn_pre, W_conv, b_conv, out0);
}